// Round 2
// baseline (399.837 us; speedup 1.0000x reference)
//
#include <hip/hip_runtime.h>

// ============================================================================
// CrossAttention fused: qkv proj (bf16 MFMA) -> flash attn -> out proj + bias
// B=2, NQ=2048, NK=4096, D=1024, H=16, HD=64, SCALE=0.125, mask-then-scale
//
// attn_k v3: 128-key iterations as two independent 64-key halves A/B so
// softmax(B) VALU overlaps PV(A) MFMA (T15-style, no extra LDS); T13
// defer-rescale; all swizzled LDS offsets + global pointers hoisted;
// Q direct-from-global (no Qs LDS); epilogue transposes via retired Ks.
// ============================================================================

typedef __attribute__((ext_vector_type(8))) short bf16x8;
typedef __attribute__((ext_vector_type(4))) short bf16x4;
typedef __attribute__((ext_vector_type(4))) float f32x4;
typedef __attribute__((ext_vector_type(4))) unsigned short u16x4;
typedef unsigned short u16;
typedef unsigned char u8;

#define DEV __device__ __forceinline__

DEV u16 f2bf(float f) {
  union { float f; unsigned int u; } x; x.f = f;
  unsigned int u = x.u;
  return (u16)((u + 0x7fffu + ((u >> 16) & 1u)) >> 16);
}

DEV unsigned cvt_pk_bf16(float lo, float hi) {
  unsigned r;
  asm("v_cvt_pk_bf16_f32 %0, %1, %2" : "=v"(r) : "v"(lo), "v"(hi));
  return r;
}

// mask-then-scale in log2 domain: bias = -1e20 * 0.125 * log2(e)
#define MASK_BIAS (-1.8033688e19f)
#define SCALE_LOG2E 0.18033688f

// ---------------------------------------------------------------------------
// Mask decode: fingerprint storage dtype (u8/bool vs int32 vs f32 vs bf16)
// and expand to f32 additive bias (MASK_BIAS if masked, 0 otherwise).
// ---------------------------------------------------------------------------
__global__ void decode_mask_k(const u8* __restrict__ raw, float* __restrict__ biasf, int n) {
  int t = threadIdx.x;
  int f_off = 0, f_gt1 = 0, f_80 = 0;
  for (int i = t; i < n; i += 256) {
    u8 bv = raw[i];
    if (bv > 1) f_gt1 = 1;
    if ((i & 3) && bv) f_off = 1;
    if (((i & 3) == 0) && bv == 0x80) f_80 = 1;
  }
  int g_gt1 = __syncthreads_or(f_gt1);
  int g_off = __syncthreads_or(f_off);
  int g_80  = __syncthreads_or(f_80);
  for (int i = t; i < n; i += 256) {
    int v;
    if (g_gt1) {
      if (g_80) v = (((const u16*)raw)[i] != 0) ? 1 : 0;      // bf16 storage
      else      v = (((const float*)raw)[i] != 0.0f) ? 1 : 0; // f32 storage
    } else if (g_off) {
      v = raw[i] ? 1 : 0;                                     // bool/u8 storage
    } else {
      v = (((const int*)raw)[i] != 0) ? 1 : 0;                // int32 storage
    }
    biasf[i] = v ? MASK_BIAS : 0.0f;
  }
}

// ---------------------------------------------------------------------------
// Projection GEMM: C = A(fp32 MxK) * W(fp32 NxK)^T, output bf16 in head layout
// [b, h, seq, 64].  M = B*seq, K = N = 1024. 128x128 tile, BK=32, 4 waves.
// ---------------------------------------------------------------------------
__global__ __launch_bounds__(256) void proj_gemm(
    const float* __restrict__ A, const float* __restrict__ W,
    u16* __restrict__ outh, int sl /* log2(seq) */)
{
  constexpr int K = 1024;
  __shared__ __align__(16) u16 As[128][40];
  __shared__ __align__(16) u16 Bs[128][40];
  const int tid = threadIdx.x;
  const int lane = tid & 63;
  const int w = tid >> 6;
  const int wm = w >> 1, wn = w & 1;
  const int bm = blockIdx.x, bn = blockIdx.y;
  const int l15 = lane & 15, lg = lane >> 4;

  f32x4 acc[4][4] = {};

  for (int k0 = 0; k0 < K; k0 += 32) {
    __syncthreads();
#pragma unroll
    for (int i = 0; i < 4; ++i) {
      int f = tid + 256 * i;       // float4 index within 128x32 tile
      int row = f >> 3, c4 = f & 7;
      float4 va = *reinterpret_cast<const float4*>(A + (size_t)(bm * 128 + row) * K + k0 + c4 * 4);
      u16x4 sa; sa[0] = f2bf(va.x); sa[1] = f2bf(va.y); sa[2] = f2bf(va.z); sa[3] = f2bf(va.w);
      *reinterpret_cast<u16x4*>(&As[row][c4 * 4]) = sa;
      float4 vb = *reinterpret_cast<const float4*>(W + (size_t)(bn * 128 + row) * K + k0 + c4 * 4);
      u16x4 sb; sb[0] = f2bf(vb.x); sb[1] = f2bf(vb.y); sb[2] = f2bf(vb.z); sb[3] = f2bf(vb.w);
      *reinterpret_cast<u16x4*>(&Bs[row][c4 * 4]) = sb;
    }
    __syncthreads();
    bf16x8 af[4], bfr[4];
#pragma unroll
    for (int mi = 0; mi < 4; ++mi)
      af[mi] = *reinterpret_cast<const bf16x8*>(&As[wm * 64 + mi * 16 + l15][lg * 8]);
#pragma unroll
    for (int ni = 0; ni < 4; ++ni)
      bfr[ni] = *reinterpret_cast<const bf16x8*>(&Bs[wn * 64 + ni * 16 + l15][lg * 8]);
#pragma unroll
    for (int mi = 0; mi < 4; ++mi)
#pragma unroll
      for (int ni = 0; ni < 4; ++ni)
        acc[mi][ni] = __builtin_amdgcn_mfma_f32_16x16x32_bf16(af[mi], bfr[ni], acc[mi][ni], 0, 0, 0);
  }

  const int seqmask = (1 << sl) - 1;
#pragma unroll
  for (int mi = 0; mi < 4; ++mi)
#pragma unroll
    for (int ni = 0; ni < 4; ++ni)
#pragma unroll
      for (int r = 0; r < 4; ++r) {
        int m = bm * 128 + wm * 64 + mi * 16 + lg * 4 + r;
        int n = bn * 128 + wn * 64 + ni * 16 + l15;
        int b = m >> sl, ml = m & seqmask;
        int h = n >> 6, hd = n & 63;
        outh[((((size_t)b * 16 + h) << sl) + ml) * 64 + hd] = f2bf(acc[mi][ni][r]);
      }
}

// ---------------------------------------------------------------------------
// Flash attention v3. 1 block = (b, h, 64-row q-tile); 4 waves x 16 q-rows.
// 128-key iterations, two 64-key halves A/B interleaved for MFMA/VALU overlap.
// Swapped QK^T: S^T[k][q], q = l15 lane-local. K row-major Ks[128][72];
// V transposed Vt[d][key0..127] (272B rows) + XOR swizzle.
// ---------------------------------------------------------------------------
__global__ __launch_bounds__(256) void attn_k(
    const u16* __restrict__ qh, const u16* __restrict__ kh, const u16* __restrict__ vh,
    const float* __restrict__ biasf, u16* __restrict__ ao)
{
  __shared__ __align__(16) u16 Ks[128][72];     // 18,432 B (also epilogue scratch)
  __shared__ __align__(16) u16 Vt[64 * 136];    // 17,408 B: [d][key], swizzled

  const int tid = threadIdx.x;
  const int lane = tid & 63;
  const int w = tid >> 6;
  const int l15 = lane & 15, lg = lane >> 4;

  // XCD-aware swizzle: each XCD owns 128 consecutive work items = 4 (b,h)
  // panels -> that XCD's KV slice (4 MB) fits its private L2.
  int bid = blockIdx.x;
  bid = (bid & 7) * 128 + (bid >> 3);
  const int qt = bid & 31;       // 32 q-tiles of 64 rows
  const int bh = bid >> 5;       // 0..31 = b*16 + h
  const int b = bh >> 4, h = bh & 15;

  const size_t base_q = ((size_t)bh * 2048 + (size_t)qt * 64) * 64;
  const size_t base_kv = (size_t)bh * 4096 * 64;

  // Q fragments direct from global (B-operand of swapped QK^T)
  bf16x8 qf[2];
  {
    const u16* qp = qh + base_q + (size_t)(w * 16 + l15) * 64 + lg * 8;
    qf[0] = *reinterpret_cast<const bf16x8*>(qp);
    qf[1] = *reinterpret_cast<const bf16x8*>(qp + 32);
  }

  f32x4 o[4] = {};                 // O^T[d = dt*16+lg*4+r][q = l15]
  float mrow = -INFINITY, lrow = 0.f;

  // staging assignments
  const int kq = tid >> 3, c8v = tid & 7;      // V: keys 4kq..4kq+3, d-chunk c8v
  const u16* kg0 = kh + base_kv + (size_t)tid * 8;              // K chunk base
  const u16* vg0 = vh + base_kv + (size_t)kq * 256 + c8v * 8;   // V chunk base
  const float* bpt = biasf + b * 4096 + lg * 4;

  // hoisted LDS offsets (constant-indexed -> stay in VGPRs)
  const int kcol = (tid & 7) * 8;
  int krow[4];
#pragma unroll
  for (int i = 0; i < 4; ++i) krow[i] = (tid + 256 * i) >> 3;
  int vst[8];
#pragma unroll
  for (int j = 0; j < 8; ++j) {
    int d = c8v * 8 + j;
    vst[j] = (d * 272 + kq * 8) ^ (((d >> 3) & 7) << 4);
  }
  int vrd[4][4];
#pragma unroll
  for (int dt = 0; dt < 4; ++dt)
#pragma unroll
    for (int n = 0; n < 4; ++n) {
      int d = dt * 16 + l15;
      vrd[dt][n] = (d * 272 + (n * 16 + lg * 4) * 2) ^ (((d >> 3) & 7) << 4);
    }

  // prefetch tile 0 into registers (T14 reg-staged)
  uint4 kr[4], vr[4];
#pragma unroll
  for (int i = 0; i < 4; ++i)
    kr[i] = *reinterpret_cast<const uint4*>(kg0 + i * 2048);
#pragma unroll
  for (int e = 0; e < 4; ++e)
    vr[e] = *reinterpret_cast<const uint4*>(vg0 + e * 64);

  for (int t = 0; t < 32; ++t) {
    __syncthreads();   // all waves done reading LDS of previous iteration
    // ---- write staged K/V into LDS ----
#pragma unroll
    for (int i = 0; i < 4; ++i)
      *reinterpret_cast<uint4*>(&Ks[krow[i]][kcol]) = kr[i];
    {
      const u16* p0 = reinterpret_cast<const u16*>(&vr[0]);
      const u16* p1 = reinterpret_cast<const u16*>(&vr[1]);
      const u16* p2 = reinterpret_cast<const u16*>(&vr[2]);
      const u16* p3 = reinterpret_cast<const u16*>(&vr[3]);
#pragma unroll
      for (int j = 0; j < 8; ++j) {
        u16x4 sv; sv[0] = p0[j]; sv[1] = p1[j]; sv[2] = p2[j]; sv[3] = p3[j];
        *reinterpret_cast<u16x4*>(reinterpret_cast<char*>(Vt) + vst[j]) = sv;
      }
    }
    // ---- issue next iteration's global loads (hidden under compute) ----
    if (t < 31) {
      kg0 += 8192; vg0 += 8192;
#pragma unroll
      for (int i = 0; i < 4; ++i)
        kr[i] = *reinterpret_cast<const uint4*>(kg0 + i * 2048);
#pragma unroll
      for (int e = 0; e < 4; ++e)
        vr[e] = *reinterpret_cast<const uint4*>(vg0 + e * 64);
    }
    __syncthreads();

    // ---- S^T for both halves: 16 MFMA ----
    f32x4 sA[4], sB[4];
    float4 bA[4];
#pragma unroll
    for (int n = 0; n < 4; ++n)
      bA[n] = *reinterpret_cast<const float4*>(bpt + n * 16);
    __builtin_amdgcn_s_setprio(1);
#pragma unroll
    for (int n = 0; n < 4; ++n) {
      f32x4 z = {};
      bf16x8 k0f = *reinterpret_cast<const bf16x8*>(&Ks[n * 16 + l15][lg * 8]);
      bf16x8 k1f = *reinterpret_cast<const bf16x8*>(&Ks[n * 16 + l15][32 + lg * 8]);
      z = __builtin_amdgcn_mfma_f32_16x16x32_bf16(k0f, qf[0], z, 0, 0, 0);
      z = __builtin_amdgcn_mfma_f32_16x16x32_bf16(k1f, qf[1], z, 0, 0, 0);
      sA[n] = z;
    }
#pragma unroll
    for (int n = 0; n < 4; ++n) {
      f32x4 z = {};
      bf16x8 k0f = *reinterpret_cast<const bf16x8*>(&Ks[64 + n * 16 + l15][lg * 8]);
      bf16x8 k1f = *reinterpret_cast<const bf16x8*>(&Ks[64 + n * 16 + l15][32 + lg * 8]);
      z = __builtin_amdgcn_mfma_f32_16x16x32_bf16(k0f, qf[0], z, 0, 0, 0);
      z = __builtin_amdgcn_mfma_f32_16x16x32_bf16(k1f, qf[1], z, 0, 0, 0);
      sB[n] = z;
    }
    __builtin_amdgcn_s_setprio(0);

    // ---- softmax half A ----
    float mt = -INFINITY;
#pragma unroll
    for (int n = 0; n < 4; ++n) {
      sA[n][0] = fmaf(sA[n][0], SCALE_LOG2E, bA[n].x);
      sA[n][1] = fmaf(sA[n][1], SCALE_LOG2E, bA[n].y);
      sA[n][2] = fmaf(sA[n][2], SCALE_LOG2E, bA[n].z);
      sA[n][3] = fmaf(sA[n][3], SCALE_LOG2E, bA[n].w);
      mt = fmaxf(mt, fmaxf(fmaxf(sA[n][0], sA[n][1]), fmaxf(sA[n][2], sA[n][3])));
    }
    mt = fmaxf(mt, __shfl_xor(mt, 16, 64));
    mt = fmaxf(mt, __shfl_xor(mt, 32, 64));
    if (__any(mt > mrow)) {            // T13: rescale only when max grows
      float mnew = fmaxf(mrow, mt);
      float a = __builtin_amdgcn_exp2f(mrow - mnew);
      mrow = mnew;
      lrow *= a;
#pragma unroll
      for (int dt = 0; dt < 4; ++dt) {
        o[dt][0] *= a; o[dt][1] *= a; o[dt][2] *= a; o[dt][3] *= a;
      }
    }
    float rs = 0.f;
#pragma unroll
    for (int n = 0; n < 4; ++n)
#pragma unroll
      for (int r = 0; r < 4; ++r) {
        float p = __builtin_amdgcn_exp2f(sA[n][r] - mrow);
        sA[n][r] = p;
        rs += p;
      }
    rs += __shfl_xor(rs, 16, 64);
    rs += __shfl_xor(rs, 32, 64);
    lrow += rs;

    bf16x4 pbfA[4];
#pragma unroll
    for (int n = 0; n < 4; ++n) {
      union { unsigned u[2]; bf16x4 v; } uu;
      uu.u[0] = cvt_pk_bf16(sA[n][0], sA[n][1]);
      uu.u[1] = cvt_pk_bf16(sA[n][2], sA[n][3]);
      pbfA[n] = uu.v;
    }

    // bias for half B (loads overlap PV_A)
    float4 bB[4];
#pragma unroll
    for (int n = 0; n < 4; ++n)
      bB[n] = *reinterpret_cast<const float4*>(bpt + 64 + n * 16);

    // ---- PV half A (MFMA) -- softmax B below is independent, overlaps ----
    __builtin_amdgcn_s_setprio(1);
#pragma unroll
    for (int dt = 0; dt < 4; ++dt)
#pragma unroll
      for (int n = 0; n < 4; ++n) {
        bf16x4 va = *reinterpret_cast<const bf16x4*>(
            reinterpret_cast<char*>(Vt) + vrd[dt][n]);
        o[dt] = __builtin_amdgcn_mfma_f32_16x16x16bf16_1k(va, pbfA[n], o[dt], 0, 0, 0);
      }
    __builtin_amdgcn_s_setprio(0);

    // ---- softmax half B ----
    float mtB = -INFINITY;
#pragma unroll
    for (int n = 0; n < 4; ++n) {
      sB[n][0] = fmaf(sB[n][0], SCALE_LOG2E, bB[n].x);
      sB[n][1] = fmaf(sB[n][1], SCALE_LOG2E, bB[n].y);
      sB[n][2] = fmaf(sB[n][2], SCALE_LOG2E, bB[n].z);
      sB[n][3] = fmaf(sB[n][3], SCALE_LOG2E, bB[n].w);
      mtB = fmaxf(mtB, fmaxf(fmaxf(sB[n][0], sB[n][1]), fmaxf(sB[n][2], sB[n][3])));
    }
    mtB = fmaxf(mtB, __shfl_xor(mtB, 16, 64));
    mtB = fmaxf(mtB, __shfl_xor(mtB, 32, 64));
    if (__any(mtB > mrow)) {
      float mnew = fmaxf(mrow, mtB);
      float a = __builtin_amdgcn_exp2f(mrow - mnew);
      mrow = mnew;
      lrow *= a;
#pragma unroll
      for (int dt = 0; dt < 4; ++dt) {
        o[dt][0] *= a; o[dt][1] *= a; o[dt][2] *= a; o[dt][3] *= a;
      }
    }
    float rsB = 0.f;
#pragma unroll
    for (int n = 0; n < 4; ++n)
#pragma unroll
      for (int r = 0; r < 4; ++r) {
        float p = __builtin_amdgcn_exp2f(sB[n][r] - mrow);
        sB[n][r] = p;
        rsB += p;
      }
    rsB += __shfl_xor(rsB, 16, 64);
    rsB += __shfl_xor(rsB, 32, 64);
    lrow += rsB;

    bf16x4 pbfB[4];
#pragma unroll
    for (int n = 0; n < 4; ++n) {
      union { unsigned u[2]; bf16x4 v; } uu;
      uu.u[0] = cvt_pk_bf16(sB[n][0], sB[n][1]);
      uu.u[1] = cvt_pk_bf16(sB[n][2], sB[n][3]);
      pbfB[n] = uu.v;
    }

    // ---- PV half B ----
    __builtin_amdgcn_s_setprio(1);
#pragma unroll
    for (int dt = 0; dt < 4; ++dt)
#pragma unroll
      for (int n = 0; n < 4; ++n) {
        bf16x4 va = *reinterpret_cast<const bf16x4*>(
            reinterpret_cast<char*>(Vt) + vrd[dt][n] + 128);
        o[dt] = __builtin_amdgcn_mfma_f32_16x16x16bf16_1k(va, pbfB[n], o[dt], 0, 0, 0);
      }
    __builtin_amdgcn_s_setprio(0);

    bpt += 128;
  }

  // ---- epilogue: normalize, transpose O^T -> O via retired Ks, store ----
  __syncthreads();   // other waves may still be reading Ks (QK of last iter)
  float rl = __builtin_amdgcn_rcpf(lrow);
#pragma unroll
  for (int dt = 0; dt < 4; ++dt) {
    unsigned p0 = cvt_pk_bf16(o[dt][0] * rl, o[dt][1] * rl);
    unsigned p1 = cvt_pk_bf16(o[dt][2] * rl, o[dt][3] * rl);
    *reinterpret_cast<unsigned*>(&Ks[w * 16 + l15][dt * 16 + lg * 4]) = p0;
    *reinterpret_cast<unsigned*>(&Ks[w * 16 + l15][dt * 16 + lg * 4 + 2]) = p1;
  }
  asm volatile("s_waitcnt lgkmcnt(0)" ::: "memory");  // wave-local: no barrier
  {
    int qr = lane >> 2, dc = (lane & 3) * 16;
    uint4 x0 = *reinterpret_cast<const uint4*>(&Ks[w * 16 + qr][dc]);
    uint4 x1 = *reinterpret_cast<const uint4*>(&Ks[w * 16 + qr][dc + 8]);
    u16* dst = ao + ((size_t)b * 2048 + qt * 64 + w * 16 + qr) * 1024 + h * 64 + dc;
    *reinterpret_cast<uint4*>(dst) = x0;
    *reinterpret_cast<uint4*>(dst + 8) = x1;
  }
}

// ---------------------------------------------------------------------------
// Output GEMM: out = Abf(bf16 4096x1024) * Wp(fp32 1024x1024)^T + bp, fp32 out
// ---------------------------------------------------------------------------
__global__ __launch_bounds__(256) void out_gemm(
    const u16* __restrict__ Abf, const float* __restrict__ W,
    const float* __restrict__ bias, float* __restrict__ out)
{
  constexpr int K = 1024, N = 1024;
  __shared__ __align__(16) u16 As[128][40];
  __shared__ __align__(16) u16 Bs[128][40];
  const int tid = threadIdx.x;
  const int lane = tid & 63;
  const int w = tid >> 6;
  const int wm = w >> 1, wn = w & 1;
  const int bm = blockIdx.x, bn = blockIdx.y;
  const int l15 = lane & 15, lg = lane >> 4;

  f32x4 acc[4][4] = {};

  for (int k0 = 0; k0 < K; k0 += 32) {
    __syncthreads();
#pragma unroll
    for (int i = 0; i < 2; ++i) {
      int f = tid + 256 * i;       // u16x8 chunk index, 128 rows x 4 chunks
      int row = f >> 2, c8 = f & 3;
      *reinterpret_cast<uint4*>(&As[row][c8 * 8]) =
          *reinterpret_cast<const uint4*>(Abf + (size_t)(bm * 128 + row) * K + k0 + c8 * 8);
    }
#pragma unroll
    for (int i = 0; i < 4; ++i) {
      int f = tid + 256 * i;
      int row = f >> 3, c4 = f & 7;
      float4 vb = *reinterpret_cast<const float4*>(W + (size_t)(bn * 128 + row) * K + k0 + c4 * 4);
      u16x4 sb; sb[0] = f2bf(vb.x); sb[1] = f2bf(vb.y); sb[2] = f2bf(vb.z); sb[3] = f2bf(vb.w);
      *reinterpret_cast<u16x4*>(&Bs[row][c4 * 4]) = sb;
    }
    __syncthreads();
    bf16x8 af[4], bfr[4];
#pragma unroll
    for (int mi = 0; mi < 4; ++mi)
      af[mi] = *reinterpret_cast<const bf16x8*>(&As[wm * 64 + mi * 16 + l15][lg * 8]);
#pragma unroll
    for (int ni = 0; ni < 4; ++ni)
      bfr[ni] = *reinterpret_cast<const bf16x8*>(&Bs[wn * 64 + ni * 16 + l15][lg * 8]);
#pragma unroll
    for (int mi = 0; mi < 4; ++mi)
#pragma unroll
      for (int ni = 0; ni < 4; ++ni)
        acc[mi][ni] = __builtin_amdgcn_mfma_f32_16x16x32_bf16(af[mi], bfr[ni], acc[mi][ni], 0, 0, 0);
  }

#pragma unroll
  for (int mi = 0; mi < 4; ++mi)
#pragma unroll
    for (int ni = 0; ni < 4; ++ni)
#pragma unroll
      for (int r = 0; r < 4; ++r) {
        int m = bm * 128 + wm * 64 + mi * 16 + lg * 4 + r;
        int n = bn * 128 + wn * 64 + ni * 16 + l15;
        out[(size_t)m * N + n] = acc[mi][ni][r] + bias[n];
      }
}

// ---------------------------------------------------------------------------
extern "C" void kernel_launch(void* const* d_in, const int* in_sizes, int n_in,
                              void* d_out, int out_size, void* d_ws, size_t ws_size,
                              hipStream_t stream) {
  const float* q  = (const float*)d_in[0];
  const float* k  = (const float*)d_in[1];
  const float* v  = (const float*)d_in[2];
  const u8* mask_raw = (const u8*)d_in[3];
  const float* Wq = (const float*)d_in[4];
  const float* Wk = (const float*)d_in[5];
  const float* Wv = (const float*)d_in[6];
  const float* Wp = (const float*)d_in[7];
  const float* bp = (const float*)d_in[8];
  float* out = (float*)d_out;

  char* ws = (char*)d_ws;
  u16* qh = (u16*)(ws);                    //  8 MB: [2,16,2048,64] bf16
  u16* kh = (u16*)(ws + 8388608);          // 16 MB: [2,16,4096,64] bf16
  u16* vh = (u16*)(ws + 25165824);         // 16 MB: [2,16,4096,64] bf16
  u16* ao = (u16*)(ws + 41943040);         //  8 MB: [2,2048,1024] bf16
  float* biasf = (float*)(ws + 50331648);  // 32 KB: decoded mask bias (f32)

  decode_mask_k<<<1, 256, 0, stream>>>(mask_raw, biasf, 8192);
  proj_gemm<<<dim3(32, 8), 256, 0, stream>>>(q, Wq, qh, 11);
  proj_gemm<<<dim3(64, 8), 256, 0, stream>>>(k, Wk, kh, 12);
  proj_gemm<<<dim3(64, 8), 256, 0, stream>>>(v, Wv, vh, 12);
  attn_k<<<1024, 256, 0, stream>>>(qh, kh, vh, biasf, ao);
  out_gemm<<<dim3(32, 8), 256, 0, stream>>>(ao, Wp, bp, out);
}

// Round 3
// 321.729 us; speedup vs baseline: 1.2428x; 1.2428x over previous
//
#include <hip/hip_runtime.h>

// ============================================================================
// CrossAttention fused: qkv proj (bf16 MFMA) -> flash attn -> out proj + bias
// B=2, NQ=2048, NK=4096, D=1024, H=16, HD=64, SCALE=0.125, mask-then-scale
//
// attn_k v4: 32 q-rows per wave (two 16-row groups) so each LDS K/V fragment
// read feeds 2 MFMAs (DS traffic per unit work halved); Vt stride-swizzle
// (136B rows) makes PV ds_read_b64 conflict-free; T13 defer-rescale per
// group; swapped QK^T in-register softmax; reg-staged prefetch; XCD swizzle.
// ============================================================================

typedef __attribute__((ext_vector_type(8))) short bf16x8;
typedef __attribute__((ext_vector_type(4))) short bf16x4;
typedef __attribute__((ext_vector_type(4))) float f32x4;
typedef __attribute__((ext_vector_type(4))) unsigned short u16x4;
typedef unsigned short u16;
typedef unsigned char u8;

#define DEV __device__ __forceinline__

DEV u16 f2bf(float f) {
  union { float f; unsigned int u; } x; x.f = f;
  unsigned int u = x.u;
  return (u16)((u + 0x7fffu + ((u >> 16) & 1u)) >> 16);
}

DEV unsigned cvt_pk_bf16(float lo, float hi) {
  unsigned r;
  asm("v_cvt_pk_bf16_f32 %0, %1, %2" : "=v"(r) : "v"(lo), "v"(hi));
  return r;
}

// mask-then-scale in log2 domain: bias = -1e20 * 0.125 * log2(e)
#define MASK_BIAS (-1.8033688e19f)
#define SCALE_LOG2E 0.18033688f

// ---------------------------------------------------------------------------
// Mask decode: fingerprint storage dtype (u8/bool vs int32 vs f32 vs bf16)
// and expand to f32 additive bias (MASK_BIAS if masked, 0 otherwise).
// ---------------------------------------------------------------------------
__global__ void decode_mask_k(const u8* __restrict__ raw, float* __restrict__ biasf, int n) {
  int t = threadIdx.x;
  int f_off = 0, f_gt1 = 0, f_80 = 0;
  for (int i = t; i < n; i += 256) {
    u8 bv = raw[i];
    if (bv > 1) f_gt1 = 1;
    if ((i & 3) && bv) f_off = 1;
    if (((i & 3) == 0) && bv == 0x80) f_80 = 1;
  }
  int g_gt1 = __syncthreads_or(f_gt1);
  int g_off = __syncthreads_or(f_off);
  int g_80  = __syncthreads_or(f_80);
  for (int i = t; i < n; i += 256) {
    int v;
    if (g_gt1) {
      if (g_80) v = (((const u16*)raw)[i] != 0) ? 1 : 0;      // bf16 storage
      else      v = (((const float*)raw)[i] != 0.0f) ? 1 : 0; // f32 storage
    } else if (g_off) {
      v = raw[i] ? 1 : 0;                                     // bool/u8 storage
    } else {
      v = (((const int*)raw)[i] != 0) ? 1 : 0;                // int32 storage
    }
    biasf[i] = v ? MASK_BIAS : 0.0f;
  }
}

// ---------------------------------------------------------------------------
// Projection GEMM: C = A(fp32 MxK) * W(fp32 NxK)^T, output bf16 in head layout
// [b, h, seq, 64].  M = B*seq, K = N = 1024. 128x128 tile, BK=32, 4 waves.
// ---------------------------------------------------------------------------
__global__ __launch_bounds__(256) void proj_gemm(
    const float* __restrict__ A, const float* __restrict__ W,
    u16* __restrict__ outh, int sl /* log2(seq) */)
{
  constexpr int K = 1024;
  __shared__ __align__(16) u16 As[128][40];
  __shared__ __align__(16) u16 Bs[128][40];
  const int tid = threadIdx.x;
  const int lane = tid & 63;
  const int w = tid >> 6;
  const int wm = w >> 1, wn = w & 1;
  const int bm = blockIdx.x, bn = blockIdx.y;
  const int l15 = lane & 15, lg = lane >> 4;

  f32x4 acc[4][4] = {};

  for (int k0 = 0; k0 < K; k0 += 32) {
    __syncthreads();
#pragma unroll
    for (int i = 0; i < 4; ++i) {
      int f = tid + 256 * i;       // float4 index within 128x32 tile
      int row = f >> 3, c4 = f & 7;
      float4 va = *reinterpret_cast<const float4*>(A + (size_t)(bm * 128 + row) * K + k0 + c4 * 4);
      u16x4 sa; sa[0] = f2bf(va.x); sa[1] = f2bf(va.y); sa[2] = f2bf(va.z); sa[3] = f2bf(va.w);
      *reinterpret_cast<u16x4*>(&As[row][c4 * 4]) = sa;
      float4 vb = *reinterpret_cast<const float4*>(W + (size_t)(bn * 128 + row) * K + k0 + c4 * 4);
      u16x4 sb; sb[0] = f2bf(vb.x); sb[1] = f2bf(vb.y); sb[2] = f2bf(vb.z); sb[3] = f2bf(vb.w);
      *reinterpret_cast<u16x4*>(&Bs[row][c4 * 4]) = sb;
    }
    __syncthreads();
    bf16x8 af[4], bfr[4];
#pragma unroll
    for (int mi = 0; mi < 4; ++mi)
      af[mi] = *reinterpret_cast<const bf16x8*>(&As[wm * 64 + mi * 16 + l15][lg * 8]);
#pragma unroll
    for (int ni = 0; ni < 4; ++ni)
      bfr[ni] = *reinterpret_cast<const bf16x8*>(&Bs[wn * 64 + ni * 16 + l15][lg * 8]);
#pragma unroll
    for (int mi = 0; mi < 4; ++mi)
#pragma unroll
      for (int ni = 0; ni < 4; ++ni)
        acc[mi][ni] = __builtin_amdgcn_mfma_f32_16x16x32_bf16(af[mi], bfr[ni], acc[mi][ni], 0, 0, 0);
  }

  const int seqmask = (1 << sl) - 1;
#pragma unroll
  for (int mi = 0; mi < 4; ++mi)
#pragma unroll
    for (int ni = 0; ni < 4; ++ni)
#pragma unroll
      for (int r = 0; r < 4; ++r) {
        int m = bm * 128 + wm * 64 + mi * 16 + lg * 4 + r;
        int n = bn * 128 + wn * 64 + ni * 16 + l15;
        int b = m >> sl, ml = m & seqmask;
        int h = n >> 6, hd = n & 63;
        outh[((((size_t)b * 16 + h) << sl) + ml) * 64 + hd] = f2bf(acc[mi][ni][r]);
      }
}

// ---------------------------------------------------------------------------
// Flash attention v4. 1 block = (b, h, 128-row q-tile); 4 waves x 32 q-rows
// (two 16-row groups per wave). KV tiles of 64. Swapped QK^T: S^T[k][q],
// q = l15 lane-local. K row-major Ks[64][72] (pad-rotation, conflict-free);
// V transposed Vt[d][key] with 136B row stride (PV reads conflict-free).
// Each K/V LDS fragment read is reused by both q-groups (DS/work halved).
// ---------------------------------------------------------------------------
__global__ __launch_bounds__(256) void attn_k(
    const u16* __restrict__ qh, const u16* __restrict__ kh, const u16* __restrict__ vh,
    const float* __restrict__ biasf, u16* __restrict__ ao)
{
  // Ks: 64*72 u16 = 9216 B ; Vt: 64 rows * 136 B = 8704 B ; total 17920 B.
  // Epilogue overlays the same LDS as Es[128][64] (16384 B).
  __shared__ __align__(16) u16 lds[8960];
  u16 (*Ks)[72] = reinterpret_cast<u16(*)[72]>(lds);
  u16* Vt = lds + 4608;

  const int tid = threadIdx.x;
  const int lane = tid & 63;
  const int w = tid >> 6;
  const int l15 = lane & 15, lg = lane >> 4;

  // XCD-aware swizzle: 512 blocks, 8 XCDs -> 64 consecutive work items per
  // XCD = 2 (b,h) panels -> KV slice fits that XCD's private L2.
  int bid = blockIdx.x;
  bid = (bid & 7) * 64 + (bid >> 3);
  const int qt = bid & 15;       // 16 q-tiles of 128 rows
  const int bh = bid >> 4;       // 0..31 = b*16 + h
  const int b = bh >> 4, h = bh & 15;

  const size_t base_kv = (size_t)bh * 4096 * 64;

  // Q fragments for both groups, direct from global
  bf16x8 qf0[2], qf1[2];
  {
    const u16* qp0 = qh + ((size_t)bh * 2048 + (size_t)qt * 128 + w * 16 + l15) * 64 + lg * 8;
    qf0[0] = *reinterpret_cast<const bf16x8*>(qp0);
    qf0[1] = *reinterpret_cast<const bf16x8*>(qp0 + 32);
    const u16* qp1 = qp0 + 64 * 64;   // +64 q-rows
    qf1[0] = *reinterpret_cast<const bf16x8*>(qp1);
    qf1[1] = *reinterpret_cast<const bf16x8*>(qp1 + 32);
  }

  f32x4 o0[4] = {}, o1[4] = {};    // O^T[d = dt*16+lg*4+r][q = l15]
  float mrow0 = -INFINITY, lrow0 = 0.f;
  float mrow1 = -INFINITY, lrow1 = 0.f;

  // staging assignments
  const int kp = tid >> 3, c8v = tid & 7;      // V: keys 2kp,2kp+1 ; d-chunk c8v
  const u16* kg = kh + base_kv + (size_t)tid * 8;
  const u16* vg = vh + base_kv + (size_t)(2 * kp) * 64 + c8v * 8;
  const float* bpt = biasf + b * 4096 + lg * 4;

  // hoisted LDS byte offsets
  const int kcol = (tid & 7) * 8;
  const int krow0 = tid >> 3, krow1 = krow0 + 32;
  int vst[8];
#pragma unroll
  for (int j = 0; j < 8; ++j)
    vst[j] = (c8v * 8 + j) * 136 + kp * 4;     // Vt[d][2kp], stride 136B
  int vrd[4][4];
#pragma unroll
  for (int dt = 0; dt < 4; ++dt)
#pragma unroll
    for (int n = 0; n < 4; ++n)
      vrd[dt][n] = (dt * 16 + l15) * 136 + (n * 16 + lg * 4) * 2;

  // prefetch tile 0 into registers (T14 reg-staged)
  uint4 kr0 = *reinterpret_cast<const uint4*>(kg);
  uint4 kr1 = *reinterpret_cast<const uint4*>(kg + 2048);
  uint4 vr0 = *reinterpret_cast<const uint4*>(vg);
  uint4 vr1 = *reinterpret_cast<const uint4*>(vg + 64);

  for (int t = 0; t < 64; ++t) {
    __syncthreads();   // all waves done reading LDS of previous tile
    // ---- write staged K/V into LDS ----
    *reinterpret_cast<uint4*>(&Ks[krow0][kcol]) = kr0;
    *reinterpret_cast<uint4*>(&Ks[krow1][kcol]) = kr1;
    {
      const u16* pa = reinterpret_cast<const u16*>(&vr0);
      const u16* pb = reinterpret_cast<const u16*>(&vr1);
#pragma unroll
      for (int j = 0; j < 8; ++j) {
        ushort2 t2; t2.x = pa[j]; t2.y = pb[j];
        *reinterpret_cast<ushort2*>(reinterpret_cast<char*>(Vt) + vst[j]) = t2;
      }
    }
    // ---- issue next tile's global loads (hidden under compute) ----
    if (t < 63) {
      kg += 4096; vg += 4096;
      kr0 = *reinterpret_cast<const uint4*>(kg);
      kr1 = *reinterpret_cast<const uint4*>(kg + 2048);
      vr0 = *reinterpret_cast<const uint4*>(vg);
      vr1 = *reinterpret_cast<const uint4*>(vg + 64);
    }
    __syncthreads();

    // ---- S^T = K Q^T, both q-groups share each K fragment ----
    f32x4 s0[4], s1[4];
    __builtin_amdgcn_s_setprio(1);
#pragma unroll
    for (int n = 0; n < 4; ++n) {
      bf16x8 k0f = *reinterpret_cast<const bf16x8*>(&Ks[n * 16 + l15][lg * 8]);
      bf16x8 k1f = *reinterpret_cast<const bf16x8*>(&Ks[n * 16 + l15][32 + lg * 8]);
      f32x4 z0 = {};
      z0 = __builtin_amdgcn_mfma_f32_16x16x32_bf16(k0f, qf0[0], z0, 0, 0, 0);
      z0 = __builtin_amdgcn_mfma_f32_16x16x32_bf16(k1f, qf0[1], z0, 0, 0, 0);
      s0[n] = z0;
      f32x4 z1 = {};
      z1 = __builtin_amdgcn_mfma_f32_16x16x32_bf16(k0f, qf1[0], z1, 0, 0, 0);
      z1 = __builtin_amdgcn_mfma_f32_16x16x32_bf16(k1f, qf1[1], z1, 0, 0, 0);
      s1[n] = z1;
    }
    __builtin_amdgcn_s_setprio(0);

    // ---- softmax group 0 ----
    {
      float mt = -INFINITY;
#pragma unroll
      for (int n = 0; n < 4; ++n) {
        float4 bv = *reinterpret_cast<const float4*>(bpt + n * 16);
        s0[n][0] = fmaf(s0[n][0], SCALE_LOG2E, bv.x);
        s0[n][1] = fmaf(s0[n][1], SCALE_LOG2E, bv.y);
        s0[n][2] = fmaf(s0[n][2], SCALE_LOG2E, bv.z);
        s0[n][3] = fmaf(s0[n][3], SCALE_LOG2E, bv.w);
        mt = fmaxf(mt, fmaxf(fmaxf(s0[n][0], s0[n][1]), fmaxf(s0[n][2], s0[n][3])));
      }
      mt = fmaxf(mt, __shfl_xor(mt, 16, 64));
      mt = fmaxf(mt, __shfl_xor(mt, 32, 64));
      if (__any(mt > mrow0)) {          // T13: exact gate (alpha=1 otherwise)
        float mnew = fmaxf(mrow0, mt);
        float a = __builtin_amdgcn_exp2f(mrow0 - mnew);
        mrow0 = mnew;
        lrow0 *= a;
#pragma unroll
        for (int dt = 0; dt < 4; ++dt) {
          o0[dt][0] *= a; o0[dt][1] *= a; o0[dt][2] *= a; o0[dt][3] *= a;
        }
      }
      float rs = 0.f;
#pragma unroll
      for (int n = 0; n < 4; ++n)
#pragma unroll
        for (int r = 0; r < 4; ++r) {
          float p = __builtin_amdgcn_exp2f(s0[n][r] - mrow0);
          s0[n][r] = p;
          rs += p;
        }
      rs += __shfl_xor(rs, 16, 64);
      rs += __shfl_xor(rs, 32, 64);
      lrow0 += rs;
    }
    bf16x4 pbf0[4];
#pragma unroll
    for (int n = 0; n < 4; ++n) {
      union { unsigned u[2]; bf16x4 v; } uu;
      uu.u[0] = cvt_pk_bf16(s0[n][0], s0[n][1]);
      uu.u[1] = cvt_pk_bf16(s0[n][2], s0[n][3]);
      pbf0[n] = uu.v;
    }

    // ---- softmax group 1 ----
    {
      float mt = -INFINITY;
#pragma unroll
      for (int n = 0; n < 4; ++n) {
        float4 bv = *reinterpret_cast<const float4*>(bpt + n * 16);
        s1[n][0] = fmaf(s1[n][0], SCALE_LOG2E, bv.x);
        s1[n][1] = fmaf(s1[n][1], SCALE_LOG2E, bv.y);
        s1[n][2] = fmaf(s1[n][2], SCALE_LOG2E, bv.z);
        s1[n][3] = fmaf(s1[n][3], SCALE_LOG2E, bv.w);
        mt = fmaxf(mt, fmaxf(fmaxf(s1[n][0], s1[n][1]), fmaxf(s1[n][2], s1[n][3])));
      }
      mt = fmaxf(mt, __shfl_xor(mt, 16, 64));
      mt = fmaxf(mt, __shfl_xor(mt, 32, 64));
      if (__any(mt > mrow1)) {
        float mnew = fmaxf(mrow1, mt);
        float a = __builtin_amdgcn_exp2f(mrow1 - mnew);
        mrow1 = mnew;
        lrow1 *= a;
#pragma unroll
        for (int dt = 0; dt < 4; ++dt) {
          o1[dt][0] *= a; o1[dt][1] *= a; o1[dt][2] *= a; o1[dt][3] *= a;
        }
      }
      float rs = 0.f;
#pragma unroll
      for (int n = 0; n < 4; ++n)
#pragma unroll
        for (int r = 0; r < 4; ++r) {
          float p = __builtin_amdgcn_exp2f(s1[n][r] - mrow1);
          s1[n][r] = p;
          rs += p;
        }
      rs += __shfl_xor(rs, 16, 64);
      rs += __shfl_xor(rs, 32, 64);
      lrow1 += rs;
    }
    bf16x4 pbf1[4];
#pragma unroll
    for (int n = 0; n < 4; ++n) {
      union { unsigned u[2]; bf16x4 v; } uu;
      uu.u[0] = cvt_pk_bf16(s1[n][0], s1[n][1]);
      uu.u[1] = cvt_pk_bf16(s1[n][2], s1[n][3]);
      pbf1[n] = uu.v;
    }

    // ---- O^T += V^T P^T, each V fragment feeds both q-groups ----
    __builtin_amdgcn_s_setprio(1);
#pragma unroll
    for (int dt = 0; dt < 4; ++dt)
#pragma unroll
      for (int n = 0; n < 4; ++n) {
        bf16x4 va = *reinterpret_cast<const bf16x4*>(
            reinterpret_cast<char*>(Vt) + vrd[dt][n]);
        o0[dt] = __builtin_amdgcn_mfma_f32_16x16x16bf16_1k(va, pbf0[n], o0[dt], 0, 0, 0);
        o1[dt] = __builtin_amdgcn_mfma_f32_16x16x16bf16_1k(va, pbf1[n], o1[dt], 0, 0, 0);
      }
    __builtin_amdgcn_s_setprio(0);

    bpt += 64;
  }

  // ---- epilogue: normalize, transpose O^T -> O via LDS overlay, store ----
  __syncthreads();   // waves may still be reading Ks/Vt of the last tile
  u16 (*Es)[64] = reinterpret_cast<u16(*)[64]>(lds);
  float rl0 = __builtin_amdgcn_rcpf(lrow0);
  float rl1 = __builtin_amdgcn_rcpf(lrow1);
#pragma unroll
  for (int dt = 0; dt < 4; ++dt) {
    unsigned a0 = cvt_pk_bf16(o0[dt][0] * rl0, o0[dt][1] * rl0);
    unsigned a1 = cvt_pk_bf16(o0[dt][2] * rl0, o0[dt][3] * rl0);
    *reinterpret_cast<unsigned*>(&Es[w * 16 + l15][dt * 16 + lg * 4]) = a0;
    *reinterpret_cast<unsigned*>(&Es[w * 16 + l15][dt * 16 + lg * 4 + 2]) = a1;
    unsigned b0 = cvt_pk_bf16(o1[dt][0] * rl1, o1[dt][1] * rl1);
    unsigned b1 = cvt_pk_bf16(o1[dt][2] * rl1, o1[dt][3] * rl1);
    *reinterpret_cast<unsigned*>(&Es[64 + w * 16 + l15][dt * 16 + lg * 4]) = b0;
    *reinterpret_cast<unsigned*>(&Es[64 + w * 16 + l15][dt * 16 + lg * 4 + 2]) = b1;
  }
  asm volatile("s_waitcnt lgkmcnt(0)" ::: "memory");  // wave-local rows only
#pragma unroll
  for (int g = 0; g < 2; ++g) {
    int qr = lane >> 2, dc = (lane & 3) * 16;
    int lr = g * 64 + w * 16 + qr;
    uint4 x0 = *reinterpret_cast<const uint4*>(&Es[lr][dc]);
    uint4 x1 = *reinterpret_cast<const uint4*>(&Es[lr][dc + 8]);
    u16* dst = ao + ((size_t)b * 2048 + (size_t)qt * 128 + lr) * 1024 + h * 64 + dc;
    *reinterpret_cast<uint4*>(dst) = x0;
    *reinterpret_cast<uint4*>(dst + 8) = x1;
  }
}

// ---------------------------------------------------------------------------
// Output GEMM: out = Abf(bf16 4096x1024) * Wp(fp32 1024x1024)^T + bp, fp32 out
// ---------------------------------------------------------------------------
__global__ __launch_bounds__(256) void out_gemm(
    const u16* __restrict__ Abf, const float* __restrict__ W,
    const float* __restrict__ bias, float* __restrict__ out)
{
  constexpr int K = 1024, N = 1024;
  __shared__ __align__(16) u16 As[128][40];
  __shared__ __align__(16) u16 Bs[128][40];
  const int tid = threadIdx.x;
  const int lane = tid & 63;
  const int w = tid >> 6;
  const int wm = w >> 1, wn = w & 1;
  const int bm = blockIdx.x, bn = blockIdx.y;
  const int l15 = lane & 15, lg = lane >> 4;

  f32x4 acc[4][4] = {};

  for (int k0 = 0; k0 < K; k0 += 32) {
    __syncthreads();
#pragma unroll
    for (int i = 0; i < 2; ++i) {
      int f = tid + 256 * i;       // u16x8 chunk index, 128 rows x 4 chunks
      int row = f >> 2, c8 = f & 3;
      *reinterpret_cast<uint4*>(&As[row][c8 * 8]) =
          *reinterpret_cast<const uint4*>(Abf + (size_t)(bm * 128 + row) * K + k0 + c8 * 8);
    }
#pragma unroll
    for (int i = 0; i < 4; ++i) {
      int f = tid + 256 * i;
      int row = f >> 3, c4 = f & 7;
      float4 vb = *reinterpret_cast<const float4*>(W + (size_t)(bn * 128 + row) * K + k0 + c4 * 4);
      u16x4 sb; sb[0] = f2bf(vb.x); sb[1] = f2bf(vb.y); sb[2] = f2bf(vb.z); sb[3] = f2bf(vb.w);
      *reinterpret_cast<u16x4*>(&Bs[row][c4 * 4]) = sb;
    }
    __syncthreads();
    bf16x8 af[4], bfr[4];
#pragma unroll
    for (int mi = 0; mi < 4; ++mi)
      af[mi] = *reinterpret_cast<const bf16x8*>(&As[wm * 64 + mi * 16 + l15][lg * 8]);
#pragma unroll
    for (int ni = 0; ni < 4; ++ni)
      bfr[ni] = *reinterpret_cast<const bf16x8*>(&Bs[wn * 64 + ni * 16 + l15][lg * 8]);
#pragma unroll
    for (int mi = 0; mi < 4; ++mi)
#pragma unroll
      for (int ni = 0; ni < 4; ++ni)
        acc[mi][ni] = __builtin_amdgcn_mfma_f32_16x16x32_bf16(af[mi], bfr[ni], acc[mi][ni], 0, 0, 0);
  }

#pragma unroll
  for (int mi = 0; mi < 4; ++mi)
#pragma unroll
    for (int ni = 0; ni < 4; ++ni)
#pragma unroll
      for (int r = 0; r < 4; ++r) {
        int m = bm * 128 + wm * 64 + mi * 16 + lg * 4 + r;
        int n = bn * 128 + wn * 64 + ni * 16 + l15;
        out[(size_t)m * N + n] = acc[mi][ni][r] + bias[n];
      }
}

// ---------------------------------------------------------------------------
extern "C" void kernel_launch(void* const* d_in, const int* in_sizes, int n_in,
                              void* d_out, int out_size, void* d_ws, size_t ws_size,
                              hipStream_t stream) {
  const float* q  = (const float*)d_in[0];
  const float* k  = (const float*)d_in[1];
  const float* v  = (const float*)d_in[2];
  const u8* mask_raw = (const u8*)d_in[3];
  const float* Wq = (const float*)d_in[4];
  const float* Wk = (const float*)d_in[5];
  const float* Wv = (const float*)d_in[6];
  const float* Wp = (const float*)d_in[7];
  const float* bp = (const float*)d_in[8];
  float* out = (float*)d_out;

  char* ws = (char*)d_ws;
  u16* qh = (u16*)(ws);                    //  8 MB: [2,16,2048,64] bf16
  u16* kh = (u16*)(ws + 8388608);          // 16 MB: [2,16,4096,64] bf16
  u16* vh = (u16*)(ws + 25165824);         // 16 MB: [2,16,4096,64] bf16
  u16* ao = (u16*)(ws + 41943040);         //  8 MB: [2,2048,1024] bf16
  float* biasf = (float*)(ws + 50331648);  // 32 KB: decoded mask bias (f32)

  decode_mask_k<<<1, 256, 0, stream>>>(mask_raw, biasf, 8192);
  proj_gemm<<<dim3(32, 8), 256, 0, stream>>>(q, Wq, qh, 11);
  proj_gemm<<<dim3(64, 8), 256, 0, stream>>>(k, Wk, kh, 12);
  proj_gemm<<<dim3(64, 8), 256, 0, stream>>>(v, Wv, vh, 12);
  attn_k<<<512, 256, 0, stream>>>(qh, kh, vh, biasf, ao);
  out_gemm<<<dim3(32, 8), 256, 0, stream>>>(ao, Wp, bp, out);
}